// Round 16
// baseline (951.737 us; speedup 1.0000x reference)
//
#include <hip/hip_runtime.h>
#include <hip/hip_cooperative_groups.h>

namespace cg = cooperative_groups;

#define N_NODES 50000
#define N_EDGES 800000
#define HEADS 4
#define NUM_GRAPHS 8
#define ZERO_WORDS 50524  // deg(50000)+gctr(1)+pad(3)+gsum(512)+gcnt(8)

struct MegaArgs {
  const int* src;
  const int* dst;
  const int* batch;
  const float *x, *fc0_w, *fc0_b, *u1, *c1, *w1, *b1, *u2, *c2, *w2, *b2, *fc1_w, *fc1_b;
  float* out;
  int* deg;
  int* gctr;
  float* gsum;
  float* gcnt;
  int* rowstart;
  int* off;
  int* src_perm;
  float *h0, *h1, *h2, *A, *P1, *P2;
};

// per-edge softmax helper (in-register, no cross-lane)
__device__ __forceinline__ float4 edge_q(float4 Ps, float b0, float b1, float b2, float b3) {
  float l0 = Ps.x + b0, l1 = Ps.y + b1, l2 = Ps.z + b2, l3 = Ps.w + b3;
  float m = fmaxf(fmaxf(l0, l1), fmaxf(l2, l3));
  float e0 = __expf(l0 - m), e1 = __expf(l1 - m), e2 = __expf(l2 - m), e3 = __expf(l3 - m);
  float inv = 1.f / (e0 + e1 + e2 + e3);
  return make_float4(e0 * inv, e1 * inv, e2 * inv, e3 * inv);
}

__global__ __launch_bounds__(256) void mega_kernel(MegaArgs a) {
  cg::grid_group grid = cg::this_grid();
  const int tid = blockIdx.x * 256 + threadIdx.x;
  const int nthreads = gridDim.x * 256;
  const int gwave = tid >> 6;
  const int nwaves = nthreads >> 6;
  const int lane = threadIdx.x & 63;

  __shared__ float sB[8192];  // 32 KB, reused per stage

  // ============ stage 0: zero deg/gctr/gsum/gcnt ============
  {
    int* zero = a.deg;  // workspace base
    for (int i = tid; i < ZERO_WORDS; i += nthreads) zero[i] = 0;
  }
  __threadfence();
  grid.sync();

  // ============ stage 1: hist (edges) + fc0/P1 (nodes) ============
  for (int i = threadIdx.x; i < 48; i += 256) sB[i] = a.fc0_w[i];
  for (int i = threadIdx.x; i < 16; i += 256) sB[48 + i] = a.fc0_b[i];
  for (int i = threadIdx.x; i < 64; i += 256) sB[64 + i] = a.u1[i];
  __syncthreads();
  for (int e = tid; e < N_EDGES; e += nthreads)
    a.off[e] = atomicAdd(&a.deg[a.dst[e]], 1);
  for (int n = tid; n < N_NODES; n += nthreads) {
    float x0 = a.x[n * 3 + 0], x1 = a.x[n * 3 + 1], x2 = a.x[n * 3 + 2];
    float h[16];
#pragma unroll
    for (int j = 0; j < 16; j++) {
      float v = x0 * sB[j] + x1 * sB[16 + j] + x2 * sB[32 + j] + sB[48 + j];
      h[j] = fmaxf(v, 0.f);
      a.h0[(size_t)n * 16 + j] = h[j];
    }
    float p0 = 0.f, p1 = 0.f, p2 = 0.f, p3 = 0.f;
#pragma unroll
    for (int j = 0; j < 16; j++) {
      p0 += h[j] * sB[64 + j * 4 + 0];
      p1 += h[j] * sB[64 + j * 4 + 1];
      p2 += h[j] * sB[64 + j * 4 + 2];
      p3 += h[j] * sB[64 + j * 4 + 3];
    }
    reinterpret_cast<float4*>(a.P1)[n] = make_float4(p0, p1, p2, p3);
  }
  __threadfence();
  grid.sync();

  // ============ stage 2: alloc (wave-aggregated bump allocation) ============
  for (int base = 0; base < N_NODES; base += nthreads) {
    int i = base + tid;
    int d = (i < N_NODES) ? a.deg[i] : 0;
    int pre = d;
#pragma unroll
    for (int o = 1; o < 64; o <<= 1) {
      int v = __shfl_up(pre, o, 64);
      if (lane >= o) pre += v;
    }
    int total = __shfl(pre, 63, 64);
    int b = 0;
    if (lane == 63) b = atomicAdd(a.gctr, total);
    b = __shfl(b, 63, 64);
    if (i < N_NODES) a.rowstart[i] = b + pre - d;
  }
  __threadfence();
  grid.sync();

  // ============ stage 3: scatter (atomic-free) ============
  for (int e = tid; e < N_EDGES; e += nthreads)
    a.src_perm[a.rowstart[a.dst[e]] + a.off[e]] = a.src[e];
  __threadfence();
  grid.sync();

  // ============ stage 4: agg1 + inline q (CIN=16) ============
  {
    const float4* P4 = reinterpret_cast<const float4*>(a.P1);
    int g = lane >> 4;
    int j = lane & 15;
    float cb0 = a.c1[0], cb1 = a.c1[1], cb2 = a.c1[2], cb3 = a.c1[3];
    for (int node = gwave; node < N_NODES; node += nwaves) {
      float4 Pd = P4[node];
      float b0 = cb0 - Pd.x, b1 = cb1 - Pd.y, b2 = cb2 - Pd.z, b3 = cb3 - Pd.w;
      int e0 = a.rowstart[node];
      int e1 = e0 + a.deg[node];
      float a0 = 0.f, a1 = 0.f, a2 = 0.f, a3 = 0.f;
      int p = e0;
      for (; p + 16 <= e1; p += 16) {
        int sA = a.src_perm[p + 0 + g];
        int sBn = a.src_perm[p + 4 + g];
        int sC = a.src_perm[p + 8 + g];
        int sD = a.src_perm[p + 12 + g];
        float4 PA = P4[sA];
        float4 PB = P4[sBn];
        float4 PC = P4[sC];
        float4 PD = P4[sD];
        float fA = a.h0[(size_t)sA * 16 + j];
        float fB = a.h0[(size_t)sBn * 16 + j];
        float fC = a.h0[(size_t)sC * 16 + j];
        float fD = a.h0[(size_t)sD * 16 + j];
        float4 qA = edge_q(PA, b0, b1, b2, b3);
        float4 qB = edge_q(PB, b0, b1, b2, b3);
        float4 qC = edge_q(PC, b0, b1, b2, b3);
        float4 qD = edge_q(PD, b0, b1, b2, b3);
        a0 += qA.x * fA + qB.x * fB + qC.x * fC + qD.x * fD;
        a1 += qA.y * fA + qB.y * fB + qC.y * fC + qD.y * fD;
        a2 += qA.z * fA + qB.z * fB + qC.z * fC + qD.z * fD;
        a3 += qA.w * fA + qB.w * fB + qC.w * fC + qD.w * fD;
      }
      for (; p + 4 <= e1; p += 4) {
        int s = a.src_perm[p + g];
        float4 Ps = P4[s];
        float f = a.h0[(size_t)s * 16 + j];
        float4 q = edge_q(Ps, b0, b1, b2, b3);
        a0 += q.x * f; a1 += q.y * f; a2 += q.z * f; a3 += q.w * f;
      }
      int rem = e1 - p;
      if (g < rem) {
        int s = a.src_perm[p + g];
        float4 Ps = P4[s];
        float f = a.h0[(size_t)s * 16 + j];
        float4 q = edge_q(Ps, b0, b1, b2, b3);
        a0 += q.x * f; a1 += q.y * f; a2 += q.z * f; a3 += q.w * f;
      }
      a0 += __shfl_xor(a0, 16, 64); a0 += __shfl_xor(a0, 32, 64);
      a1 += __shfl_xor(a1, 16, 64); a1 += __shfl_xor(a1, 32, 64);
      a2 += __shfl_xor(a2, 16, 64); a2 += __shfl_xor(a2, 32, 64);
      a3 += __shfl_xor(a3, 16, 64); a3 += __shfl_xor(a3, 32, 64);
      float o = (g == 0) ? a0 : (g == 1) ? a1 : (g == 2) ? a2 : a3;
      a.A[(size_t)node * 64 + lane] = o;
    }
  }
  __threadfence();
  grid.sync();

  // ============ stage 5: gemm1 + fused proj2 ============
  for (int i = threadIdx.x; i < 2048; i += 256) {
    int hj = i / 32, c = i % 32;
    sB[i] = a.w1[(hj % 16) * 128 + (hj / 16) * 32 + c];
  }
  for (int i = threadIdx.x; i < 128; i += 256) sB[2048 + i] = a.u2[i];
  __syncthreads();
  {
    const float4* sB4 = reinterpret_cast<const float4*>(sB);
    const float* sU = sB + 2048;
    int c4 = threadIdx.x & 7;
    int gg = threadIdx.x >> 3;
    int ntiles = (N_NODES + 63) / 64;
    for (int bt = blockIdx.x; bt < ntiles; bt += gridDim.x) {
      int n0 = bt * 64 + gg * 2;
      int n1 = n0 + 1;
      int na = min(n0, N_NODES - 1);
      int nb = min(n1, N_NODES - 1);
      const float4* A0 = reinterpret_cast<const float4*>(a.A + (size_t)na * 64);
      const float4* A1 = reinterpret_cast<const float4*>(a.A + (size_t)nb * 64);
      float4 bc = reinterpret_cast<const float4*>(a.b1)[c4];
      float4 acc0 = {0, 0, 0, 0}, acc1 = {0, 0, 0, 0};
#pragma unroll 2
      for (int k4 = 0; k4 < 16; k4++) {
        float4 a0 = A0[k4];
        float4 a1 = A1[k4];
        float4 w0 = sB4[(4 * k4 + 0) * 8 + c4];
        float4 wv1 = sB4[(4 * k4 + 1) * 8 + c4];
        float4 w2v = sB4[(4 * k4 + 2) * 8 + c4];
        float4 w3 = sB4[(4 * k4 + 3) * 8 + c4];
        acc0.x += a0.x * w0.x + a0.y * wv1.x + a0.z * w2v.x + a0.w * w3.x;
        acc0.y += a0.x * w0.y + a0.y * wv1.y + a0.z * w2v.y + a0.w * w3.y;
        acc0.z += a0.x * w0.z + a0.y * wv1.z + a0.z * w2v.z + a0.w * w3.z;
        acc0.w += a0.x * w0.w + a0.y * wv1.w + a0.z * w2v.w + a0.w * w3.w;
        acc1.x += a1.x * w0.x + a1.y * wv1.x + a1.z * w2v.x + a1.w * w3.x;
        acc1.y += a1.x * w0.y + a1.y * wv1.y + a1.z * w2v.y + a1.w * w3.y;
        acc1.z += a1.x * w0.z + a1.y * wv1.z + a1.z * w2v.z + a1.w * w3.z;
        acc1.w += a1.x * w0.w + a1.y * wv1.w + a1.z * w2v.w + a1.w * w3.w;
      }
      float inv0 = 1.f / fmaxf((float)a.deg[na], 1.f);
      float inv1 = 1.f / fmaxf((float)a.deg[nb], 1.f);
      float4 o0 = {fmaxf(acc0.x * inv0 + bc.x, 0.f), fmaxf(acc0.y * inv0 + bc.y, 0.f),
                   fmaxf(acc0.z * inv0 + bc.z, 0.f), fmaxf(acc0.w * inv0 + bc.w, 0.f)};
      float4 o1 = {fmaxf(acc1.x * inv1 + bc.x, 0.f), fmaxf(acc1.y * inv1 + bc.y, 0.f),
                   fmaxf(acc1.z * inv1 + bc.z, 0.f), fmaxf(acc1.w * inv1 + bc.w, 0.f)};
      if (n0 < N_NODES) reinterpret_cast<float4*>(a.h1 + (size_t)n0 * 32)[c4] = o0;
      if (n1 < N_NODES) reinterpret_cast<float4*>(a.h1 + (size_t)n1 * 32)[c4] = o1;
      float pa[4] = {0, 0, 0, 0}, pb[4] = {0, 0, 0, 0};
#pragma unroll
      for (int k = 0; k < 4; k++) {
        int c = 4 * c4 + k;
        float v0 = k == 0 ? o0.x : k == 1 ? o0.y : k == 2 ? o0.z : o0.w;
        float v1 = k == 0 ? o1.x : k == 1 ? o1.y : k == 2 ? o1.z : o1.w;
#pragma unroll
        for (int hh = 0; hh < 4; hh++) {
          pa[hh] += v0 * sU[c * 4 + hh];
          pb[hh] += v1 * sU[c * 4 + hh];
        }
      }
#pragma unroll
      for (int msk = 1; msk <= 4; msk <<= 1) {
#pragma unroll
        for (int hh = 0; hh < 4; hh++) {
          pa[hh] += __shfl_xor(pa[hh], msk, 64);
          pb[hh] += __shfl_xor(pb[hh], msk, 64);
        }
      }
      if (c4 == 0) {
        if (n0 < N_NODES)
          reinterpret_cast<float4*>(a.P2)[n0] = make_float4(pa[0], pa[1], pa[2], pa[3]);
        if (n1 < N_NODES)
          reinterpret_cast<float4*>(a.P2)[n1] = make_float4(pb[0], pb[1], pb[2], pb[3]);
      }
    }
  }
  __threadfence();
  grid.sync();

  // ============ stage 6: agg2 + inline q (CIN=32) ============
  {
    const float4* P4 = reinterpret_cast<const float4*>(a.P2);
    int g = lane >> 5;
    int j = lane & 31;
    float cb0 = a.c2[0], cb1 = a.c2[1], cb2 = a.c2[2], cb3 = a.c2[3];
    for (int node = gwave; node < N_NODES; node += nwaves) {
      float4 Pd = P4[node];
      float b0 = cb0 - Pd.x, b1 = cb1 - Pd.y, b2 = cb2 - Pd.z, b3 = cb3 - Pd.w;
      int e0 = a.rowstart[node];
      int e1 = e0 + a.deg[node];
      float a0 = 0.f, a1 = 0.f, a2 = 0.f, a3 = 0.f;
      int p = e0;
      for (; p + 8 <= e1; p += 8) {
        int sA = a.src_perm[p + 0 + g];
        int sBn = a.src_perm[p + 2 + g];
        int sC = a.src_perm[p + 4 + g];
        int sD = a.src_perm[p + 6 + g];
        float4 PA = P4[sA];
        float4 PB = P4[sBn];
        float4 PC = P4[sC];
        float4 PD = P4[sD];
        float fA = a.h1[(size_t)sA * 32 + j];
        float fB = a.h1[(size_t)sBn * 32 + j];
        float fC = a.h1[(size_t)sC * 32 + j];
        float fD = a.h1[(size_t)sD * 32 + j];
        float4 qA = edge_q(PA, b0, b1, b2, b3);
        float4 qB = edge_q(PB, b0, b1, b2, b3);
        float4 qC = edge_q(PC, b0, b1, b2, b3);
        float4 qD = edge_q(PD, b0, b1, b2, b3);
        a0 += qA.x * fA + qB.x * fB + qC.x * fC + qD.x * fD;
        a1 += qA.y * fA + qB.y * fB + qC.y * fC + qD.y * fD;
        a2 += qA.z * fA + qB.z * fB + qC.z * fC + qD.z * fD;
        a3 += qA.w * fA + qB.w * fB + qC.w * fC + qD.w * fD;
      }
      for (; p + 2 <= e1; p += 2) {
        int s = a.src_perm[p + g];
        float4 Ps = P4[s];
        float f = a.h1[(size_t)s * 32 + j];
        float4 q = edge_q(Ps, b0, b1, b2, b3);
        a0 += q.x * f; a1 += q.y * f; a2 += q.z * f; a3 += q.w * f;
      }
      int rem = e1 - p;
      if (g < rem) {
        int s = a.src_perm[p + g];
        float4 Ps = P4[s];
        float f = a.h1[(size_t)s * 32 + j];
        float4 q = edge_q(Ps, b0, b1, b2, b3);
        a0 += q.x * f; a1 += q.y * f; a2 += q.z * f; a3 += q.w * f;
      }
      a0 += __shfl_xor(a0, 32, 64);
      a1 += __shfl_xor(a1, 32, 64);
      a2 += __shfl_xor(a2, 32, 64);
      a3 += __shfl_xor(a3, 32, 64);
      float oa = (g == 0) ? a0 : a1;
      float ob = (g == 0) ? a2 : a3;
      a.A[(size_t)node * 128 + lane] = oa;
      a.A[(size_t)node * 128 + 64 + lane] = ob;
    }
  }
  __threadfence();
  grid.sync();

  // ============ stage 7: gemm2 ============
  for (int i = threadIdx.x; i < 8192; i += 256) {
    int hj = i / 64, c = i % 64;
    sB[i] = a.w2[(hj % 32) * 256 + (hj / 32) * 64 + c];
  }
  __syncthreads();
  {
    const float4* sB4 = reinterpret_cast<const float4*>(sB);
    int c4 = threadIdx.x & 15;
    int gg = threadIdx.x >> 4;
    int ntiles = (N_NODES + 31) / 32;
    for (int bt = blockIdx.x; bt < ntiles; bt += gridDim.x) {
      int n0 = bt * 32 + gg * 2;
      int n1 = n0 + 1;
      int na = min(n0, N_NODES - 1);
      int nb = min(n1, N_NODES - 1);
      const float4* A0 = reinterpret_cast<const float4*>(a.A + (size_t)na * 128);
      const float4* A1 = reinterpret_cast<const float4*>(a.A + (size_t)nb * 128);
      float4 bc = reinterpret_cast<const float4*>(a.b2)[c4];
      float4 acc0 = {0, 0, 0, 0}, acc1 = {0, 0, 0, 0};
#pragma unroll 2
      for (int k4 = 0; k4 < 32; k4++) {
        float4 a0 = A0[k4];
        float4 a1 = A1[k4];
        float4 w0 = sB4[(4 * k4 + 0) * 16 + c4];
        float4 wv1 = sB4[(4 * k4 + 1) * 16 + c4];
        float4 w2v = sB4[(4 * k4 + 2) * 16 + c4];
        float4 w3 = sB4[(4 * k4 + 3) * 16 + c4];
        acc0.x += a0.x * w0.x + a0.y * wv1.x + a0.z * w2v.x + a0.w * w3.x;
        acc0.y += a0.x * w0.y + a0.y * wv1.y + a0.z * w2v.y + a0.w * w3.y;
        acc0.z += a0.x * w0.z + a0.y * wv1.z + a0.z * w2v.z + a0.w * w3.z;
        acc0.w += a0.x * w0.w + a0.y * wv1.w + a0.z * w2v.w + a0.w * w3.w;
        acc1.x += a1.x * w0.x + a1.y * wv1.x + a1.z * w2v.x + a1.w * w3.x;
        acc1.y += a1.x * w0.y + a1.y * wv1.y + a1.z * w2v.y + a1.w * w3.y;
        acc1.z += a1.x * w0.z + a1.y * wv1.z + a1.z * w2v.z + a1.w * w3.z;
        acc1.w += a1.x * w0.w + a1.y * wv1.w + a1.z * w2v.w + a1.w * w3.w;
      }
      if (n0 < N_NODES) {
        float inv = 1.f / fmaxf((float)a.deg[n0], 1.f);
        float4 o = {fmaxf(acc0.x * inv + bc.x, 0.f), fmaxf(acc0.y * inv + bc.y, 0.f),
                    fmaxf(acc0.z * inv + bc.z, 0.f), fmaxf(acc0.w * inv + bc.w, 0.f)};
        reinterpret_cast<float4*>(a.h2 + (size_t)n0 * 64)[c4] = o;
      }
      if (n1 < N_NODES) {
        float inv = 1.f / fmaxf((float)a.deg[n1], 1.f);
        float4 o = {fmaxf(acc1.x * inv + bc.x, 0.f), fmaxf(acc1.y * inv + bc.y, 0.f),
                    fmaxf(acc1.z * inv + bc.z, 0.f), fmaxf(acc1.w * inv + bc.w, 0.f)};
        reinterpret_cast<float4*>(a.h2 + (size_t)n1 * 64)[c4] = o;
      }
    }
  }
  __threadfence();
  grid.sync();

  // ============ stage 8: pool (per-graph mean, batch sorted) ============
  {
    int c = lane;
    int nchunks = (N_NODES + 63) / 64;
    for (int chunk = gwave; chunk < nchunks; chunk += nwaves) {
      int n0 = chunk * 64;
      int n1 = min(n0 + 64, N_NODES);
      float acc = 0.f;
      float cacc = 0.f;
      int curg = a.batch[n0];
      for (int n = n0; n < n1; n++) {
        int g = a.batch[n];
        float v = a.h2[(size_t)n * 64 + c];
        if (g != curg) {
          atomicAdd(&a.gsum[curg * 64 + c], acc);
          if (c == 0) atomicAdd(&a.gcnt[curg], cacc);
          acc = 0.f;
          cacc = 0.f;
          curg = g;
        }
        acc += v;
        cacc += 1.f;
      }
      atomicAdd(&a.gsum[curg * 64 + c], acc);
      if (c == 0) atomicAdd(&a.gcnt[curg], cacc);
    }
  }
  __threadfence();
  grid.sync();

  // ============ stage 9: head ============
  if (blockIdx.x == 0 && threadIdx.x < NUM_GRAPHS * 10) {
    int g = threadIdx.x / 10, k = threadIdx.x % 10;
    float inv = 1.f / fmaxf(a.gcnt[g], 1.f);
    float s = a.fc1_b[k];
#pragma unroll
    for (int c = 0; c < 64; c++) s += a.gsum[g * 64 + c] * inv * a.fc1_w[c * 10 + k];
    a.out[g * 10 + k] = s;
  }
}

extern "C" void kernel_launch(void* const* d_in, const int* in_sizes, int n_in,
                              void* d_out, int out_size, void* d_ws, size_t ws_size,
                              hipStream_t stream) {
  MegaArgs a;
  a.x = (const float*)d_in[0];
  const int* edge_index = (const int*)d_in[1];
  a.batch = (const int*)d_in[2];
  a.fc0_w = (const float*)d_in[3];
  a.fc0_b = (const float*)d_in[4];
  a.u1 = (const float*)d_in[5];
  a.c1 = (const float*)d_in[6];
  a.w1 = (const float*)d_in[7];
  a.b1 = (const float*)d_in[8];
  a.u2 = (const float*)d_in[9];
  a.c2 = (const float*)d_in[10];
  a.w2 = (const float*)d_in[11];
  a.b2 = (const float*)d_in[12];
  a.fc1_w = (const float*)d_in[13];
  a.fc1_b = (const float*)d_in[14];
  a.out = (float*)d_out;
  a.src = edge_index;            // x_j
  a.dst = edge_index + N_EDGES;  // x_i

  // ---- workspace layout (4-byte words; zero region [0,50524) handled by stage 0) ----
  char* wsb = (char*)d_ws;
  a.deg = (int*)wsb;                              // N
  a.gctr = a.deg + N_NODES;                       // 1
  a.gsum = (float*)wsb + 50004;                   // 512
  a.gcnt = a.gsum + NUM_GRAPHS * 64;              // 8
  a.rowstart = (int*)wsb + 50524;                 // N
  a.off = a.rowstart + N_NODES;                   // E
  a.src_perm = a.off + N_EDGES;                   // E
  a.h0 = (float*)wsb + 1700524;                   // N*16
  a.h1 = a.h0 + (size_t)N_NODES * 16;             // N*32
  a.h2 = a.h1 + (size_t)N_NODES * 32;             // N*64
  a.A = a.h2 + (size_t)N_NODES * 64;              // N*128
  a.P1 = a.A + (size_t)N_NODES * 128;             // N*4
  a.P2 = a.P1 + (size_t)N_NODES * 4;              // N*4

  // Cooperative grid sizing: occupancy query x CU count (deterministic per device).
  int dev = 0;
  hipGetDevice(&dev);
  int numCU = 0;
  hipDeviceGetAttribute(&numCU, hipDeviceAttributeMultiprocessorCount, dev);
  int blocksPerCU = 0;
  hipOccupancyMaxActiveBlocksPerMultiprocessor(&blocksPerCU, (const void*)mega_kernel, 256, 0);
  if (numCU <= 0) numCU = 256;
  if (blocksPerCU <= 0) blocksPerCU = 1;
  int G = numCU * blocksPerCU;

  void* args[] = {(void*)&a};
  hipLaunchCooperativeKernel((const void*)mega_kernel, dim3(G), dim3(256), args, 0, stream);
}

// Round 17
// 275.255 us; speedup vs baseline: 3.4577x; 3.4577x over previous
//
#include <hip/hip_runtime.h>

#define N_NODES 50000
#define N_EDGES 800000
#define HEADS 4
#define NUM_GRAPHS 8

#define EBLK ((N_EDGES + 255) / 256)   // 3125
#define NBLK ((N_NODES + 255) / 256)   // 196

// ============ Fused: hist (edge blocks) + fc0/P1 (node blocks) ============
__global__ __launch_bounds__(256) void hist_fc0_kernel(
    const int* __restrict__ dst, int* __restrict__ deg, int* __restrict__ off,
    const float* __restrict__ x,
    const float* __restrict__ fc0_w, const float* __restrict__ fc0_b,
    const float* __restrict__ u1,
    float* __restrict__ h0, float* __restrict__ P1) {
  if (blockIdx.x < EBLK) {
    int e = blockIdx.x * 256 + threadIdx.x;
    if (e < N_EDGES) off[e] = atomicAdd(&deg[dst[e]], 1);
    return;
  }
  __shared__ float sW0[3 * 16];
  __shared__ float sB0[16];
  __shared__ float sU[16 * 4];
  for (int i = threadIdx.x; i < 48; i += 256) sW0[i] = fc0_w[i];
  for (int i = threadIdx.x; i < 16; i += 256) sB0[i] = fc0_b[i];
  for (int i = threadIdx.x; i < 64; i += 256) sU[i] = u1[i];
  __syncthreads();
  int n = (blockIdx.x - EBLK) * 256 + threadIdx.x;
  if (n >= N_NODES) return;
  float x0 = x[n * 3 + 0], x1 = x[n * 3 + 1], x2 = x[n * 3 + 2];
  float h[16];
#pragma unroll
  for (int j = 0; j < 16; j++) {
    float v = x0 * sW0[0 * 16 + j] + x1 * sW0[1 * 16 + j] + x2 * sW0[2 * 16 + j] + sB0[j];
    h[j] = fmaxf(v, 0.f);
    h0[(size_t)n * 16 + j] = h[j];
  }
  float p0 = 0.f, p1 = 0.f, p2 = 0.f, p3 = 0.f;
#pragma unroll
  for (int j = 0; j < 16; j++) {
    p0 += h[j] * sU[j * 4 + 0];
    p1 += h[j] * sU[j * 4 + 1];
    p2 += h[j] * sU[j * 4 + 2];
    p3 += h[j] * sU[j * 4 + 3];
  }
  reinterpret_cast<float4*>(P1)[n] = make_float4(p0, p1, p2, p3);
}

// Wave-aggregated bump allocation.
__global__ __launch_bounds__(256) void alloc_kernel(const int* __restrict__ deg,
                                                    int* __restrict__ gctr,
                                                    int* __restrict__ rowstart) {
  int i = blockIdx.x * blockDim.x + threadIdx.x;
  int lane = threadIdx.x & 63;
  int d = (i < N_NODES) ? deg[i] : 0;
  int pre = d;
#pragma unroll
  for (int offd = 1; offd < 64; offd <<= 1) {
    int v = __shfl_up(pre, offd, 64);
    if (lane >= offd) pre += v;
  }
  int total = __shfl(pre, 63, 64);
  int base = 0;
  if (lane == 63) base = atomicAdd(gctr, total);
  base = __shfl(base, 63, 64);
  if (i < N_NODES) rowstart[i] = base + pre - d;
}

// src_perm[rowstart[dst]+off] = src — atomic-free random scatter.
__global__ __launch_bounds__(256) void scatter_kernel(const int* __restrict__ src,
                                                      const int* __restrict__ dst,
                                                      const int* __restrict__ rowstart,
                                                      const int* __restrict__ off,
                                                      int* __restrict__ src_perm) {
  int e = blockIdx.x * blockDim.x + threadIdx.x;
  if (e >= N_EDGES) return;
  src_perm[rowstart[dst[e]] + off[e]] = src[e];
}

// per-edge softmax helper (in-register, no cross-lane)
__device__ __forceinline__ float4 edge_q(float4 Ps, float b0, float b1, float b2, float b3) {
  float l0 = Ps.x + b0, l1 = Ps.y + b1, l2 = Ps.z + b2, l3 = Ps.w + b3;
  float m = fmaxf(fmaxf(l0, l1), fmaxf(l2, l3));
  float e0 = __expf(l0 - m), e1 = __expf(l1 - m), e2 = __expf(l2 - m), e3 = __expf(l3 - m);
  float inv = 1.f / (e0 + e1 + e2 + e3);
  return make_float4(e0 * inv, e1 * inv, e2 * inv, e3 * inv);
}

// ============ AGG1 + inline q (CIN=16): 4 edges in parallel per wave ============
__global__ __launch_bounds__(256) void agg1_kernel(
    const int* __restrict__ rowstart, const int* __restrict__ deg,
    const int* __restrict__ src_perm,
    const float* __restrict__ P1, const float* __restrict__ c1,
    const float* __restrict__ h0,
    float* __restrict__ A) {
  int wave = threadIdx.x >> 6;
  int lane = threadIdx.x & 63;
  int g = lane >> 4;
  int j = lane & 15;
  int node = blockIdx.x * 4 + wave;
  if (node >= N_NODES) return;
  float4 Pd = reinterpret_cast<const float4*>(P1)[node];
  float b0 = c1[0] - Pd.x, b1 = c1[1] - Pd.y, b2 = c1[2] - Pd.z, b3 = c1[3] - Pd.w;
  int e0 = rowstart[node];
  int e1 = e0 + deg[node];
  const float4* P4 = reinterpret_cast<const float4*>(P1);
  float a0 = 0.f, a1 = 0.f, a2 = 0.f, a3 = 0.f;
  int p = e0;
  for (; p + 16 <= e1; p += 16) {
    int sA = src_perm[p + 0 + g];
    int sB = src_perm[p + 4 + g];
    int sC = src_perm[p + 8 + g];
    int sD = src_perm[p + 12 + g];
    float4 PA = P4[sA];
    float4 PB = P4[sB];
    float4 PC = P4[sC];
    float4 PD = P4[sD];
    float fA = h0[(size_t)sA * 16 + j];
    float fB = h0[(size_t)sB * 16 + j];
    float fC = h0[(size_t)sC * 16 + j];
    float fD = h0[(size_t)sD * 16 + j];
    float4 qA = edge_q(PA, b0, b1, b2, b3);
    float4 qB = edge_q(PB, b0, b1, b2, b3);
    float4 qC = edge_q(PC, b0, b1, b2, b3);
    float4 qD = edge_q(PD, b0, b1, b2, b3);
    a0 += qA.x * fA + qB.x * fB + qC.x * fC + qD.x * fD;
    a1 += qA.y * fA + qB.y * fB + qC.y * fC + qD.y * fD;
    a2 += qA.z * fA + qB.z * fB + qC.z * fC + qD.z * fD;
    a3 += qA.w * fA + qB.w * fB + qC.w * fC + qD.w * fD;
  }
  for (; p + 4 <= e1; p += 4) {
    int s = src_perm[p + g];
    float4 Ps = P4[s];
    float f = h0[(size_t)s * 16 + j];
    float4 q = edge_q(Ps, b0, b1, b2, b3);
    a0 += q.x * f; a1 += q.y * f; a2 += q.z * f; a3 += q.w * f;
  }
  int rem = e1 - p;
  if (g < rem) {
    int s = src_perm[p + g];
    float4 Ps = P4[s];
    float f = h0[(size_t)s * 16 + j];
    float4 q = edge_q(Ps, b0, b1, b2, b3);
    a0 += q.x * f; a1 += q.y * f; a2 += q.z * f; a3 += q.w * f;
  }
  a0 += __shfl_xor(a0, 16, 64); a0 += __shfl_xor(a0, 32, 64);
  a1 += __shfl_xor(a1, 16, 64); a1 += __shfl_xor(a1, 32, 64);
  a2 += __shfl_xor(a2, 16, 64); a2 += __shfl_xor(a2, 32, 64);
  a3 += __shfl_xor(a3, 16, 64); a3 += __shfl_xor(a3, 32, 64);
  float o = (g == 0) ? a0 : (g == 1) ? a1 : (g == 2) ? a2 : a3;
  A[(size_t)node * 64 + lane] = o;  // A[node][g*16+j]
}

// ============ AGG2 + inline q (CIN=32): 2 edges in parallel per wave ============
__global__ __launch_bounds__(256) void agg2_kernel(
    const int* __restrict__ rowstart, const int* __restrict__ deg,
    const int* __restrict__ src_perm,
    const float* __restrict__ P2, const float* __restrict__ c2,
    const float* __restrict__ h1,
    float* __restrict__ A) {
  int wave = threadIdx.x >> 6;
  int lane = threadIdx.x & 63;
  int g = lane >> 5;
  int j = lane & 31;
  int node = blockIdx.x * 4 + wave;
  if (node >= N_NODES) return;
  float4 Pd = reinterpret_cast<const float4*>(P2)[node];
  float b0 = c2[0] - Pd.x, b1 = c2[1] - Pd.y, b2 = c2[2] - Pd.z, b3 = c2[3] - Pd.w;
  int e0 = rowstart[node];
  int e1 = e0 + deg[node];
  const float4* P4 = reinterpret_cast<const float4*>(P2);
  float a0 = 0.f, a1 = 0.f, a2 = 0.f, a3 = 0.f;
  int p = e0;
  for (; p + 8 <= e1; p += 8) {
    int sA = src_perm[p + 0 + g];
    int sB = src_perm[p + 2 + g];
    int sC = src_perm[p + 4 + g];
    int sD = src_perm[p + 6 + g];
    float4 PA = P4[sA];
    float4 PB = P4[sB];
    float4 PC = P4[sC];
    float4 PD = P4[sD];
    float fA = h1[(size_t)sA * 32 + j];
    float fB = h1[(size_t)sB * 32 + j];
    float fC = h1[(size_t)sC * 32 + j];
    float fD = h1[(size_t)sD * 32 + j];
    float4 qA = edge_q(PA, b0, b1, b2, b3);
    float4 qB = edge_q(PB, b0, b1, b2, b3);
    float4 qC = edge_q(PC, b0, b1, b2, b3);
    float4 qD = edge_q(PD, b0, b1, b2, b3);
    a0 += qA.x * fA + qB.x * fB + qC.x * fC + qD.x * fD;
    a1 += qA.y * fA + qB.y * fB + qC.y * fC + qD.y * fD;
    a2 += qA.z * fA + qB.z * fB + qC.z * fC + qD.z * fD;
    a3 += qA.w * fA + qB.w * fB + qC.w * fC + qD.w * fD;
  }
  for (; p + 2 <= e1; p += 2) {
    int s = src_perm[p + g];
    float4 Ps = P4[s];
    float f = h1[(size_t)s * 32 + j];
    float4 q = edge_q(Ps, b0, b1, b2, b3);
    a0 += q.x * f; a1 += q.y * f; a2 += q.z * f; a3 += q.w * f;
  }
  int rem = e1 - p;
  if (g < rem) {
    int s = src_perm[p + g];
    float4 Ps = P4[s];
    float f = h1[(size_t)s * 32 + j];
    float4 q = edge_q(Ps, b0, b1, b2, b3);
    a0 += q.x * f; a1 += q.y * f; a2 += q.z * f; a3 += q.w * f;
  }
  a0 += __shfl_xor(a0, 32, 64);
  a1 += __shfl_xor(a1, 32, 64);
  a2 += __shfl_xor(a2, 32, 64);
  a3 += __shfl_xor(a3, 32, 64);
  float oa = (g == 0) ? a0 : a1;
  float ob = (g == 0) ? a2 : a3;
  A[(size_t)node * 128 + lane] = oa;        // [g*32+j]
  A[(size_t)node * 128 + 64 + lane] = ob;   // [(g+2)*32+j]
}

// ============ GEMM1 + fused proj2: h1 = relu((A1@B1)/deg + b1); P2 = h1·u2 ============
__global__ __launch_bounds__(256) void gemm1_kernel(
    const int* __restrict__ deg, const float* __restrict__ A,
    const float* __restrict__ w1, const float* __restrict__ b1,
    const float* __restrict__ u2,
    float* __restrict__ h1, float* __restrict__ P2) {
  __shared__ float sB[64 * 32];   // 8 KB
  __shared__ float sU[32 * 4];
  for (int i = threadIdx.x; i < 64 * 32; i += 256) {
    int hj = i / 32, c = i % 32;
    sB[i] = w1[(hj % 16) * 128 + (hj / 16) * 32 + c];
  }
  for (int i = threadIdx.x; i < 128; i += 256) sU[i] = u2[i];
  __syncthreads();
  const float4* sB4 = reinterpret_cast<const float4*>(sB);
  int c4 = threadIdx.x & 7;
  int g = threadIdx.x >> 3;
  int n0 = blockIdx.x * 64 + g * 2;
  int n1 = n0 + 1;
  int na = min(n0, N_NODES - 1);
  int nb = min(n1, N_NODES - 1);
  const float4* A0 = reinterpret_cast<const float4*>(A + (size_t)na * 64);
  const float4* A1 = reinterpret_cast<const float4*>(A + (size_t)nb * 64);
  float4 bc = reinterpret_cast<const float4*>(b1)[c4];
  float4 acc0 = {0, 0, 0, 0}, acc1 = {0, 0, 0, 0};
#pragma unroll 2
  for (int k4 = 0; k4 < 16; k4++) {
    float4 a0 = A0[k4];
    float4 a1 = A1[k4];
    float4 w0 = sB4[(4 * k4 + 0) * 8 + c4];
    float4 wv1 = sB4[(4 * k4 + 1) * 8 + c4];
    float4 w2v = sB4[(4 * k4 + 2) * 8 + c4];
    float4 w3 = sB4[(4 * k4 + 3) * 8 + c4];
    acc0.x += a0.x * w0.x + a0.y * wv1.x + a0.z * w2v.x + a0.w * w3.x;
    acc0.y += a0.x * w0.y + a0.y * wv1.y + a0.z * w2v.y + a0.w * w3.y;
    acc0.z += a0.x * w0.z + a0.y * wv1.z + a0.z * w2v.z + a0.w * w3.z;
    acc0.w += a0.x * w0.w + a0.y * wv1.w + a0.z * w2v.w + a0.w * w3.w;
    acc1.x += a1.x * w0.x + a1.y * wv1.x + a1.z * w2v.x + a1.w * w3.x;
    acc1.y += a1.x * w0.y + a1.y * wv1.y + a1.z * w2v.y + a1.w * w3.y;
    acc1.z += a1.x * w0.z + a1.y * wv1.z + a1.z * w2v.z + a1.w * w3.z;
    acc1.w += a1.x * w0.w + a1.y * wv1.w + a1.z * w2v.w + a1.w * w3.w;
  }
  float inv0 = 1.f / fmaxf((float)deg[na], 1.f);
  float inv1 = 1.f / fmaxf((float)deg[nb], 1.f);
  float4 o0 = {fmaxf(acc0.x * inv0 + bc.x, 0.f), fmaxf(acc0.y * inv0 + bc.y, 0.f),
               fmaxf(acc0.z * inv0 + bc.z, 0.f), fmaxf(acc0.w * inv0 + bc.w, 0.f)};
  float4 o1 = {fmaxf(acc1.x * inv1 + bc.x, 0.f), fmaxf(acc1.y * inv1 + bc.y, 0.f),
               fmaxf(acc1.z * inv1 + bc.z, 0.f), fmaxf(acc1.w * inv1 + bc.w, 0.f)};
  if (n0 < N_NODES) reinterpret_cast<float4*>(h1 + (size_t)n0 * 32)[c4] = o0;
  if (n1 < N_NODES) reinterpret_cast<float4*>(h1 + (size_t)n1 * 32)[c4] = o1;
  float pa[4] = {0, 0, 0, 0}, pb[4] = {0, 0, 0, 0};
#pragma unroll
  for (int k = 0; k < 4; k++) {
    int c = 4 * c4 + k;
    float v0 = k == 0 ? o0.x : k == 1 ? o0.y : k == 2 ? o0.z : o0.w;
    float v1 = k == 0 ? o1.x : k == 1 ? o1.y : k == 2 ? o1.z : o1.w;
#pragma unroll
    for (int hh = 0; hh < 4; hh++) {
      pa[hh] += v0 * sU[c * 4 + hh];
      pb[hh] += v1 * sU[c * 4 + hh];
    }
  }
#pragma unroll
  for (int msk = 1; msk <= 4; msk <<= 1) {
#pragma unroll
    for (int hh = 0; hh < 4; hh++) {
      pa[hh] += __shfl_xor(pa[hh], msk, 64);
      pb[hh] += __shfl_xor(pb[hh], msk, 64);
    }
  }
  if (c4 == 0) {
    if (n0 < N_NODES)
      reinterpret_cast<float4*>(P2)[n0] = make_float4(pa[0], pa[1], pa[2], pa[3]);
    if (n1 < N_NODES)
      reinterpret_cast<float4*>(P2)[n1] = make_float4(pb[0], pb[1], pb[2], pb[3]);
  }
}

// ============ GEMM2: h2 = relu((A2 @ B2)/deg + b2), A2:[N,128], B2:[128,64] ============
__global__ __launch_bounds__(256) void gemm2_kernel(
    const int* __restrict__ deg, const float* __restrict__ A,
    const float* __restrict__ w2, const float* __restrict__ b2,
    float* __restrict__ h2) {
  __shared__ float sB[128 * 64];  // 32 KB
  for (int i = threadIdx.x; i < 128 * 64; i += 256) {
    int hj = i / 64, c = i % 64;
    sB[i] = w2[(hj % 32) * 256 + (hj / 32) * 64 + c];
  }
  __syncthreads();
  const float4* sB4 = reinterpret_cast<const float4*>(sB);
  int c4 = threadIdx.x & 15;
  int g = threadIdx.x >> 4;
  int n0 = blockIdx.x * 32 + g * 2;
  int n1 = n0 + 1;
  int na = min(n0, N_NODES - 1);
  int nb = min(n1, N_NODES - 1);
  const float4* A0 = reinterpret_cast<const float4*>(A + (size_t)na * 128);
  const float4* A1 = reinterpret_cast<const float4*>(A + (size_t)nb * 128);
  float4 bc = reinterpret_cast<const float4*>(b2)[c4];
  float4 acc0 = {0, 0, 0, 0}, acc1 = {0, 0, 0, 0};
#pragma unroll 2
  for (int k4 = 0; k4 < 32; k4++) {
    float4 a0 = A0[k4];
    float4 a1 = A1[k4];
    float4 w0 = sB4[(4 * k4 + 0) * 16 + c4];
    float4 wv1 = sB4[(4 * k4 + 1) * 16 + c4];
    float4 w2v = sB4[(4 * k4 + 2) * 16 + c4];
    float4 w3 = sB4[(4 * k4 + 3) * 16 + c4];
    acc0.x += a0.x * w0.x + a0.y * wv1.x + a0.z * w2v.x + a0.w * w3.x;
    acc0.y += a0.x * w0.y + a0.y * wv1.y + a0.z * w2v.y + a0.w * w3.y;
    acc0.z += a0.x * w0.z + a0.y * wv1.z + a0.z * w2v.z + a0.w * w3.z;
    acc0.w += a0.x * w0.w + a0.y * wv1.w + a0.z * w2v.w + a0.w * w3.w;
    acc1.x += a1.x * w0.x + a1.y * wv1.x + a1.z * w2v.x + a1.w * w3.x;
    acc1.y += a1.x * w0.y + a1.y * wv1.y + a1.z * w2v.y + a1.w * w3.y;
    acc1.z += a1.x * w0.z + a1.y * wv1.z + a1.z * w2v.z + a1.w * w3.z;
    acc1.w += a1.x * w0.w + a1.y * wv1.w + a1.z * w2v.w + a1.w * w3.w;
  }
  if (n0 < N_NODES) {
    float inv = 1.f / fmaxf((float)deg[n0], 1.f);
    float4 o = {fmaxf(acc0.x * inv + bc.x, 0.f), fmaxf(acc0.y * inv + bc.y, 0.f),
                fmaxf(acc0.z * inv + bc.z, 0.f), fmaxf(acc0.w * inv + bc.w, 0.f)};
    reinterpret_cast<float4*>(h2 + (size_t)n0 * 64)[c4] = o;
  }
  if (n1 < N_NODES) {
    float inv = 1.f / fmaxf((float)deg[n1], 1.f);
    float4 o = {fmaxf(acc1.x * inv + bc.x, 0.f), fmaxf(acc1.y * inv + bc.y, 0.f),
                fmaxf(acc1.z * inv + bc.z, 0.f), fmaxf(acc1.w * inv + bc.w, 0.f)};
    reinterpret_cast<float4*>(h2 + (size_t)n1 * 64)[c4] = o;
  }
}

// ============ Pool: per-graph mean of h2 (batch sorted) ============
#define POOL_CHUNK 64
__global__ __launch_bounds__(256) void pool_kernel(
    const float* __restrict__ h2, const int* __restrict__ batch,
    float* __restrict__ gsum, float* __restrict__ gcnt) {
  int grp = threadIdx.x / 64;
  int c = threadIdx.x % 64;
  int n0 = (blockIdx.x * 4 + grp) * POOL_CHUNK;
  int n1 = min(n0 + POOL_CHUNK, N_NODES);
  if (n0 >= N_NODES) return;
  float acc = 0.f;
  float cacc = 0.f;
  int curg = batch[n0];
  for (int n = n0; n < n1; n++) {
    int g = batch[n];
    float v = h2[(size_t)n * 64 + c];
    if (g != curg) {
      atomicAdd(&gsum[curg * 64 + c], acc);
      if (c == 0) atomicAdd(&gcnt[curg], cacc);
      acc = 0.f;
      cacc = 0.f;
      curg = g;
    }
    acc += v;
    cacc += 1.f;
  }
  atomicAdd(&gsum[curg * 64 + c], acc);
  if (c == 0) atomicAdd(&gcnt[curg], cacc);
}

// ============ Head: out = (gsum/gcnt) @ fc1_w + fc1_b ============
__global__ __launch_bounds__(128) void head_kernel(
    const float* __restrict__ gsum, const float* __restrict__ gcnt,
    const float* __restrict__ fc1_w, const float* __restrict__ fc1_b,
    float* __restrict__ out) {
  int t = threadIdx.x;
  if (t >= NUM_GRAPHS * 10) return;
  int g = t / 10, k = t % 10;
  float inv = 1.f / fmaxf(gcnt[g], 1.f);
  float s = fc1_b[k];
#pragma unroll
  for (int c = 0; c < 64; c++) s += gsum[g * 64 + c] * inv * fc1_w[c * 10 + k];
  out[g * 10 + k] = s;
}

extern "C" void kernel_launch(void* const* d_in, const int* in_sizes, int n_in,
                              void* d_out, int out_size, void* d_ws, size_t ws_size,
                              hipStream_t stream) {
  const float* x = (const float*)d_in[0];
  const int* edge_index = (const int*)d_in[1];
  const int* batch = (const int*)d_in[2];
  const float* fc0_w = (const float*)d_in[3];
  const float* fc0_b = (const float*)d_in[4];
  const float* u1 = (const float*)d_in[5];
  const float* c1 = (const float*)d_in[6];
  const float* w1 = (const float*)d_in[7];
  const float* b1 = (const float*)d_in[8];
  const float* u2 = (const float*)d_in[9];
  const float* c2 = (const float*)d_in[10];
  const float* w2 = (const float*)d_in[11];
  const float* b2 = (const float*)d_in[12];
  const float* fc1_w = (const float*)d_in[13];
  const float* fc1_b = (const float*)d_in[14];
  float* out = (float*)d_out;

  const int* src = edge_index;            // x_j
  const int* dst = edge_index + N_EDGES;  // x_i

  // ---- workspace layout (4-byte words) ----
  char* wsb = (char*)d_ws;
  int* deg = (int*)wsb;                          // N
  int* gctr = deg + N_NODES;                     // 1
  float* gsum = (float*)wsb + 50004;             // 512
  float* gcnt = gsum + NUM_GRAPHS * 64;          // 8   (zero region ends 50524)
  int* rowstart = (int*)wsb + 50524;             // N
  int* off = rowstart + N_NODES;                 // E
  int* src_perm = off + N_EDGES;                 // E
  float* h0 = (float*)wsb + 1700524;             // N*16
  float* h1 = h0 + (size_t)N_NODES * 16;         // N*32
  float* h2 = h1 + (size_t)N_NODES * 32;         // N*64
  float* A = h2 + (size_t)N_NODES * 64;          // N*128
  float* P1 = A + (size_t)N_NODES * 128;         // N*4
  float* P2 = P1 + (size_t)N_NODES * 4;          // N*4

  hipMemsetAsync(d_ws, 0, 50524 * sizeof(int), stream);

  int nblk = NBLK;
  int eblk = EBLK;
  int wblk = (N_NODES + 3) / 4;  // wave-per-node kernels, 4 waves/block

  // hist + fc0/P1 (independent; one grid)
  hist_fc0_kernel<<<eblk + nblk, 256, 0, stream>>>(dst, deg, off, x, fc0_w, fc0_b, u1, h0, P1);
  alloc_kernel<<<nblk, 256, 0, stream>>>(deg, gctr, rowstart);
  scatter_kernel<<<eblk, 256, 0, stream>>>(src, dst, rowstart, off, src_perm);

  // FeaStConv 1: agg (inline q) -> GEMM (+ fused P2)
  agg1_kernel<<<wblk, 256, 0, stream>>>(rowstart, deg, src_perm, P1, c1, h0, A);
  gemm1_kernel<<<(N_NODES + 63) / 64, 256, 0, stream>>>(deg, A, w1, b1, u2, h1, P2);

  // FeaStConv 2: agg (inline q) -> GEMM
  agg2_kernel<<<wblk, 256, 0, stream>>>(rowstart, deg, src_perm, P2, c2, h1, A);
  gemm2_kernel<<<(N_NODES + 31) / 32, 256, 0, stream>>>(deg, A, w2, b2, h2);

  // Pool + head
  int pblk = (N_NODES + POOL_CHUNK * 4 - 1) / (POOL_CHUNK * 4);
  pool_kernel<<<pblk, 256, 0, stream>>>(h2, batch, gsum, gcnt);
  head_kernel<<<1, 128, 0, stream>>>(gsum, gcnt, fc1_w, fc1_b, out);
}